// Round 6
// baseline (483.445 us; speedup 1.0000x reference)
//
#include <hip/hip_runtime.h>
#include <hip/hip_bf16.h>

// Problem constants
constexpr int DIMD  = 1152;
constexpr int NHD   = 12;     // query heads
constexpr int KVHD  = 2;      // kv heads
constexpr int HDD   = 96;     // head dim
constexpr int GRPS  = 6;      // GQA group size
constexpr int SEQL  = 2048;
constexpr int BSZ4  = 4;
constexpr int MROWS = BSZ4 * SEQL;           // 8192
constexpr int NQKV  = DIMD + 2 * KVHD * HDD; // 1536
constexpr float SCALE  = 0.10206207261596577f; // 96^-0.5
constexpr float SCALE2 = 0.14724444f;          // SCALE * log2(e)

typedef short  bf16x8 __attribute__((ext_vector_type(8)));
typedef float  f32x4  __attribute__((ext_vector_type(4)));

typedef __attribute__((address_space(3))) unsigned int       lds_u32_t;
typedef __attribute__((address_space(1))) const unsigned int glb_u32_t;

__device__ __forceinline__ void gload16(const unsigned short* g, unsigned short* l) {
    // async global->LDS DMA, 16B/lane; LDS dest = wave-uniform base + lane*16
    __builtin_amdgcn_global_load_lds((glb_u32_t*)(const void*)g,
                                     (lds_u32_t*)(void*)l, 16, 0, 0);
}

__device__ __forceinline__ unsigned short f2bf(float f) {
    unsigned int u = __builtin_bit_cast(unsigned int, f);
    u += 0x7fff + ((u >> 16) & 1);   // RNE
    return (unsigned short)(u >> 16);
}

// ---------------------------------------------------------------------------
// Fused fp32 -> bf16 convert for x | q_w | kv_w | wo_w (dst regions contiguous)
// ---------------------------------------------------------------------------
constexpr int CP0 = (MROWS * DIMD) / 4;                    // x
constexpr int CP1 = CP0 + (DIMD * DIMD) / 4;               // q_w
constexpr int CP2 = CP1 + (2 * KVHD * HDD * DIMD) / 4;     // kv_w
constexpr int CP3 = CP2 + (DIMD * DIMD) / 4;               // wo_w

__global__ __launch_bounds__(256) void cvt_all_kernel(
    const float4* __restrict__ x,   const float4* __restrict__ qw,
    const float4* __restrict__ kvw, const float4* __restrict__ wow,
    ushort4* __restrict__ dst)
{
    int i = blockIdx.x * 256 + threadIdx.x;   // grid == CP3 exactly
    const float4* s; int j;
    if (i < CP0)      { s = x;   j = i; }
    else if (i < CP1) { s = qw;  j = i - CP0; }
    else if (i < CP2) { s = kvw; j = i - CP1; }
    else              { s = wow; j = i - CP2; }
    float4 f = s[j];
    ushort4 o;
    o.x = f2bf(f.x); o.y = f2bf(f.y); o.z = f2bf(f.z); o.w = f2bf(f.w);
    dst[i] = o;
}

// ---------------------------------------------------------------------------
// Kernel 1: QKV projection, bf16 MFMA (m97 structure) + bias + RoPE + scatter
// (unchanged from R3-R5)
// ---------------------------------------------------------------------------
__global__ __launch_bounds__(256) void qkv_mfma_kernel(
    const unsigned short* __restrict__ xb,  const unsigned short* __restrict__ qwb,
    const unsigned short* __restrict__ kvwb,
    const float* __restrict__ qb,  const float* __restrict__ kvb,
    const int* __restrict__ start_pos,
    unsigned short* __restrict__ Qo, unsigned short* __restrict__ Ko,
    unsigned short* __restrict__ VTo)
{
    __shared__ __align__(16) unsigned short As[128 * 32];
    __shared__ __align__(16) unsigned short Bs[128 * 32];

    const int tid  = threadIdx.x;
    const int w    = tid >> 6;
    const int lane = tid & 63;
    const int l16  = lane & 15;
    const int quad = lane >> 4;
    const int wm   = w >> 1, wn = w & 1;
    const int m0   = blockIdx.y * 128;
    const int n0   = blockIdx.x * 128;

    const unsigned short* Abase = xb + (size_t)m0 * DIMD;
    const unsigned short* Bbase = (n0 < DIMD)
        ? qwb  + (size_t)n0 * DIMD
        : kvwb + (size_t)(n0 - DIMD) * DIMD;

    const int srow = w * 16 + (lane >> 2);
    const int scol = (lane & 3) * 8;

    f32x4 acc[4][4];
    #pragma unroll
    for (int mi = 0; mi < 4; mi++)
        #pragma unroll
        for (int ni = 0; ni < 4; ni++) acc[mi][ni] = (f32x4){0.f, 0.f, 0.f, 0.f};

    for (int k0 = 0; k0 < DIMD; k0 += 32) {
        gload16(Abase + (size_t)srow        * DIMD + k0 + scol, &As[w * 512]);
        gload16(Abase + (size_t)(srow + 64) * DIMD + k0 + scol, &As[2048 + w * 512]);
        gload16(Bbase + (size_t)srow        * DIMD + k0 + scol, &Bs[w * 512]);
        gload16(Bbase + (size_t)(srow + 64) * DIMD + k0 + scol, &Bs[2048 + w * 512]);
        __syncthreads();
        bf16x8 af[4], bfr[4];
        #pragma unroll
        for (int mi = 0; mi < 4; mi++)
            af[mi] = *(const bf16x8*)&As[(wm * 64 + mi * 16 + l16) * 32 + quad * 8];
        #pragma unroll
        for (int ni = 0; ni < 4; ni++)
            bfr[ni] = *(const bf16x8*)&Bs[(wn * 64 + ni * 16 + l16) * 32 + quad * 8];
        #pragma unroll
        for (int mi = 0; mi < 4; mi++)
            #pragma unroll
            for (int ni = 0; ni < 4; ni++)
                acc[mi][ni] = __builtin_amdgcn_mfma_f32_16x16x32_bf16(
                    af[mi], bfr[ni], acc[mi][ni], 0, 0, 0);
        __syncthreads();
    }

    const int sp = *start_pos;
    #pragma unroll
    for (int ni = 0; ni < 4; ni++) {
        const int n   = n0 + wn * 64 + ni * 16 + l16;
        const bool isQ = (n < DIMD);
        const int jj  = n - DIMD;
        const bool isK = !isQ && (jj < KVHD * HDD);
        const int d   = isQ ? (n % HDD) : (jj % HDD);
        const int hh  = isQ ? (n / HDD) : ((jj / HDD) & 1);
        const float bias = isQ ? qb[n] : kvb[jj];
        const bool doRope = isQ || isK;
        const int de = d & ~1;
        const float th = doRope ? powf(10000.0f, -(float)de / 96.0f) : 0.0f;
        const float sg = (n & 1) ? 1.0f : -1.0f;
        #pragma unroll
        for (int mi = 0; mi < 4; mi++) {
            #pragma unroll
            for (int r = 0; r < 4; r++) {
                const int m = m0 + wm * 64 + mi * 16 + quad * 4 + r;
                const int b = m >> 11;
                const int s = m & (SEQL - 1);
                float v  = acc[mi][ni][r] + bias;
                float pv = __shfl_xor(v, 1, 64);
                float o = v;
                if (doRope) {
                    float ang = (float)(s + sp) * th;
                    float sn, cs; sincosf(ang, &sn, &cs);
                    o = v * cs + sg * pv * sn;
                }
                if (isQ)
                    Qo[(((size_t)b * NHD + hh) * SEQL + s) * HDD + d] = f2bf(o);
                else if (isK)
                    Ko[(((size_t)b * KVHD + hh) * SEQL + s) * HDD + d] = f2bf(o);
                else
                    VTo[(((size_t)b * KVHD + hh) * HDD + d) * SEQL + s] = f2bf(o);
            }
        }
    }
}

// ---------------------------------------------------------------------------
// Kernel 2: bf16 MFMA causal flash attention, Round 6.
//  - 32 q-rows per wave (two 16-q groups), 128 q-rows/WG: K/V fragment reads
//    amortized over 2x MFMA; barriers + staging per MFMA halved.
//  - Single-buffered K/V staging (global_load_lds); TLP hides latency.
//  - S^T = K*Q^T lane-local softmax, base-2 exp; P buffer reused across
//    the two q-groups (wave-private, wave_barrier sequenced).
// LDS: Ks 13.3K + VTs 13.8K + Ps 9.2K + Al 0.5K = 37.4 KB.
// ---------------------------------------------------------------------------
__global__ __launch_bounds__(256, 3) void attn_mfma_kernel(
    const unsigned short* __restrict__ Q, const unsigned short* __restrict__ K,
    const unsigned short* __restrict__ VT, unsigned short* __restrict__ AO)
{
    __shared__ __align__(16) unsigned short Ks[64 * 104];   // 13 16B-slots/row
    __shared__ __align__(16) unsigned short VTs[96 * 72];   // 9 16B-slots/row
    __shared__ __align__(16) unsigned short Ps[4][16 * 72]; // per-wave P buffer
    __shared__ float Al[4][32];                             // per-wave bcast

    const int tid  = threadIdx.x;
    const int w    = tid >> 6;
    const int lane = tid & 63;
    const int l16  = lane & 15;
    const int quad = lane >> 4;
    const int qt   = (int)(gridDim.x - 1) - (int)blockIdx.x;  // heavy first
    const int h    = blockIdx.y;
    const int b    = blockIdx.z;
    const int kvh  = h / GRPS;
    const int nkb  = 2 * qt + 2;

    const unsigned short* Qbase  = Q  + (((size_t)b * NHD  + h)   * SEQL) * HDD;
    const unsigned short* Kbase  = K  + (((size_t)b * KVHD + kvh) * SEQL) * HDD;
    const unsigned short* VTbase = VT + (((size_t)b * KVHD + kvh) * HDD)  * SEQL;

    // --- staging maps: 27 gload16 slots/WG, instr i = w + 4*j (j = 0..6)
    int goff[7]; int gkind[7]; unsigned short* gdst[7];
    #pragma unroll
    for (int j = 0; j < 7; j++) {
        const int i = w + 4 * j;
        gkind[j] = 2; goff[j] = 0; gdst[j] = nullptr;
        if (i < 13) {
            int slot = i * 64 + lane;
            int r = slot / 13, g = slot - r * 13;
            goff[j]  = r * HDD + (g < 12 ? g * 8 : 0);
            gkind[j] = 0;
            gdst[j]  = &Ks[i * 512];
        } else if (i < 27) {
            int iv = i - 13;
            int slot = iv * 64 + lane;
            if (slot < 864) {
                int r = slot / 9, g = slot - r * 9;
                goff[j]  = r * SEQL + (g < 8 ? g * 8 : 0);
                gkind[j] = 1;
                gdst[j]  = &VTs[iv * 512];
            }
        }
    }

    // --- Q fragments: group g covers rows qt*128 + g*64 + w*16 + [0,16)
    bf16x8 qf[2][3];
    #pragma unroll
    for (int g = 0; g < 2; g++) {
        const int qrow = qt * 128 + g * 64 + w * 16 + l16;
        const unsigned short* qp = Qbase + (size_t)qrow * HDD + quad * 8;
        qf[g][0] = *(const bf16x8*)(qp);
        qf[g][1] = *(const bf16x8*)(qp + 32);
        qf[g][2] = *(const bf16x8*)(qp + 64);
    }

    float m_r[2] = {-1e30f, -1e30f};
    float l_r[2] = {0.0f, 0.0f};
    f32x4 oacc[2][6];
    #pragma unroll
    for (int g = 0; g < 2; g++)
        #pragma unroll
        for (int nn = 0; nn < 6; nn++) oacc[g][nn] = (f32x4){0.f, 0.f, 0.f, 0.f};

    for (int kb = 0; kb < nkb; kb++) {
        const int k0 = kb * 64;
        // ---- stage K (64x96) + V^T (96x64) via async DMA
        #pragma unroll
        for (int j = 0; j < 7; j++) {
            if (gkind[j] == 0)
                gload16(Kbase + (size_t)k0 * HDD + goff[j], gdst[j]);
            else if (gkind[j] == 1) {
                if ((w + 4 * j) < 26 || lane < 32)
                    gload16(VTbase + k0 + goff[j], gdst[j]);
            }
        }
        __syncthreads();

        const bool do0 = (kb <= 2 * qt);   // group0 fully masked on last kblock

        // ---- S^T = K * Q^T for both q-groups (K frags read once)
        f32x4 s[2][4];
        #pragma unroll
        for (int n = 0; n < 4; n++) {
            const unsigned short* kr = &Ks[(n * 16 + l16) * 104 + quad * 8];
            bf16x8 kf0 = *(const bf16x8*)(kr);
            bf16x8 kf1 = *(const bf16x8*)(kr + 32);
            bf16x8 kf2 = *(const bf16x8*)(kr + 64);
            f32x4 a1 = (f32x4){0.f, 0.f, 0.f, 0.f};
            a1 = __builtin_amdgcn_mfma_f32_16x16x32_bf16(kf0, qf[1][0], a1, 0, 0, 0);
            a1 = __builtin_amdgcn_mfma_f32_16x16x32_bf16(kf1, qf[1][1], a1, 0, 0, 0);
            a1 = __builtin_amdgcn_mfma_f32_16x16x32_bf16(kf2, qf[1][2], a1, 0, 0, 0);
            s[1][n] = a1;
            if (do0) {
                f32x4 a0 = (f32x4){0.f, 0.f, 0.f, 0.f};
                a0 = __builtin_amdgcn_mfma_f32_16x16x32_bf16(kf0, qf[0][0], a0, 0, 0, 0);
                a0 = __builtin_amdgcn_mfma_f32_16x16x32_bf16(kf1, qf[0][1], a0, 0, 0, 0);
                a0 = __builtin_amdgcn_mfma_f32_16x16x32_bf16(kf2, qf[0][2], a0, 0, 0, 0);
                s[0][n] = a0;
            }
        }

        // ---- softmax per group (base-2), P via reused wave-private buffer
        bf16x8 pa[2][2];
        float albr[2][4];
        #pragma unroll
        for (int g = 0; g < 2; g++) {
            if (g == 0 && !do0) continue;
            const int qabs = qt * 128 + g * 64 + w * 16 + l16;
            float v[4][4];
            float mx = -3e30f;
            #pragma unroll
            for (int n = 0; n < 4; n++)
                #pragma unroll
                for (int r = 0; r < 4; r++) {
                    const int t = k0 + n * 16 + quad * 4 + r;
                    float x = s[g][n][r] * SCALE2;
                    if (t > qabs) x = -1e30f;
                    v[n][r] = x;
                    mx = fmaxf(mx, x);
                }
            mx = fmaxf(mx, __shfl_xor(mx, 16, 64));
            mx = fmaxf(mx, __shfl_xor(mx, 32, 64));
            const float mnew = fmaxf(m_r[g], mx);
            const float al = exp2f(m_r[g] - mnew);
            float sum = 0.0f;
            #pragma unroll
            for (int n = 0; n < 4; n++) {
                float p0 = exp2f(v[n][0] - mnew);
                float p1 = exp2f(v[n][1] - mnew);
                float p2 = exp2f(v[n][2] - mnew);
                float p3 = exp2f(v[n][3] - mnew);
                sum += (p0 + p1) + (p2 + p3);
                ushort4 pk;
                pk.x = f2bf(p0); pk.y = f2bf(p1); pk.z = f2bf(p2); pk.w = f2bf(p3);
                *(ushort4*)&Ps[w][l16 * 72 + n * 16 + quad * 4] = pk;
            }
            sum += __shfl_xor(sum, 16, 64);
            sum += __shfl_xor(sum, 32, 64);
            l_r[g] = l_r[g] * al + sum;
            m_r[g] = mnew;
            if (quad == 0) Al[w][g * 16 + l16] = al;
            __builtin_amdgcn_wave_barrier();
            pa[g][0] = *(const bf16x8*)&Ps[w][l16 * 72 + quad * 8];
            pa[g][1] = *(const bf16x8*)&Ps[w][l16 * 72 + 32 + quad * 8];
            const float4 a4 = *(const float4*)&Al[w][g * 16 + quad * 4];
            albr[g][0] = a4.x; albr[g][1] = a4.y; albr[g][2] = a4.z; albr[g][3] = a4.w;
            __builtin_amdgcn_wave_barrier();   // reads done before next overwrite
        }

        // ---- O = diag(alpha) O + P V  (V frags read once, used by both groups)
        #pragma unroll
        for (int nn = 0; nn < 6; nn++) {
            const unsigned short* vr = &VTs[(nn * 16 + l16) * 72 + quad * 8];
            bf16x8 vb0 = *(const bf16x8*)(vr);
            bf16x8 vb1 = *(const bf16x8*)(vr + 32);
            if (do0) {
                f32x4 a = oacc[0][nn];
                #pragma unroll
                for (int r = 0; r < 4; r++) a[r] *= albr[0][r];
                a = __builtin_amdgcn_mfma_f32_16x16x32_bf16(pa[0][0], vb0, a, 0, 0, 0);
                a = __builtin_amdgcn_mfma_f32_16x16x32_bf16(pa[0][1], vb1, a, 0, 0, 0);
                oacc[0][nn] = a;
            }
            f32x4 a = oacc[1][nn];
            #pragma unroll
            for (int r = 0; r < 4; r++) a[r] *= albr[1][r];
            a = __builtin_amdgcn_mfma_f32_16x16x32_bf16(pa[1][0], vb0, a, 0, 0, 0);
            a = __builtin_amdgcn_mfma_f32_16x16x32_bf16(pa[1][1], vb1, a, 0, 0, 0);
            oacc[1][nn] = a;
        }
        __syncthreads();
    }

    // ---- epilogue: normalize + bf16 store
    #pragma unroll
    for (int g = 0; g < 2; g++) {
        const float linv = 1.0f / l_r[g];
        if (quad == 0) Al[w][g * 16 + l16] = linv;
    }
    __builtin_amdgcn_wave_barrier();
    #pragma unroll
    for (int g = 0; g < 2; g++) {
        const float4 lb4 = *(const float4*)&Al[w][g * 16 + quad * 4];
        const float lbr[4] = {lb4.x, lb4.y, lb4.z, lb4.w};
        const int row0 = qt * 128 + g * 64 + w * 16 + quad * 4;
        #pragma unroll
        for (int nn = 0; nn < 6; nn++) {
            #pragma unroll
            for (int r = 0; r < 4; r++) {
                AO[((size_t)b * SEQL + row0 + r) * DIMD + h * HDD + nn * 16 + l16] =
                    f2bf(oacc[g][nn][r] * lbr[r]);
            }
        }
    }
}

// ---------------------------------------------------------------------------
// Kernel 3: output projection, bf16 MFMA (unchanged from R3-R5)
// ---------------------------------------------------------------------------
__global__ __launch_bounds__(256) void out_mfma_kernel(
    const unsigned short* __restrict__ Ab, const unsigned short* __restrict__ Wb,
    const float* __restrict__ wob, float* __restrict__ out)
{
    __shared__ __align__(16) unsigned short As[128 * 32];
    __shared__ __align__(16) unsigned short Bs[128 * 32];

    const int tid  = threadIdx.x;
    const int w    = tid >> 6;
    const int lane = tid & 63;
    const int l16  = lane & 15;
    const int quad = lane >> 4;
    const int wm   = w >> 1, wn = w & 1;
    const int m0   = blockIdx.y * 128;
    const int n0   = blockIdx.x * 128;

    const unsigned short* Abase = Ab + (size_t)m0 * DIMD;
    const unsigned short* Bbase = Wb + (size_t)n0 * DIMD;

    const int srow = w * 16 + (lane >> 2);
    const int scol = (lane & 3) * 8;

    f32x4 acc[4][4];
    #pragma unroll
    for (int mi = 0; mi < 4; mi++)
        #pragma unroll
        for (int ni = 0; ni < 4; ni++) acc[mi][ni] = (f32x4){0.f, 0.f, 0.f, 0.f};

    for (int k0 = 0; k0 < DIMD; k0 += 32) {
        gload16(Abase + (size_t)srow        * DIMD + k0 + scol, &As[w * 512]);
        gload16(Abase + (size_t)(srow + 64) * DIMD + k0 + scol, &As[2048 + w * 512]);
        gload16(Bbase + (size_t)srow        * DIMD + k0 + scol, &Bs[w * 512]);
        gload16(Bbase + (size_t)(srow + 64) * DIMD + k0 + scol, &Bs[2048 + w * 512]);
        __syncthreads();
        bf16x8 af[4], bfr[4];
        #pragma unroll
        for (int mi = 0; mi < 4; mi++)
            af[mi] = *(const bf16x8*)&As[(wm * 64 + mi * 16 + l16) * 32 + quad * 8];
        #pragma unroll
        for (int ni = 0; ni < 4; ni++)
            bfr[ni] = *(const bf16x8*)&Bs[(wn * 64 + ni * 16 + l16) * 32 + quad * 8];
        #pragma unroll
        for (int mi = 0; mi < 4; mi++)
            #pragma unroll
            for (int ni = 0; ni < 4; ni++)
                acc[mi][ni] = __builtin_amdgcn_mfma_f32_16x16x32_bf16(
                    af[mi], bfr[ni], acc[mi][ni], 0, 0, 0);
        __syncthreads();
    }

    #pragma unroll
    for (int ni = 0; ni < 4; ni++) {
        const int n = n0 + wn * 64 + ni * 16 + l16;
        const float bias = wob[n];
        #pragma unroll
        for (int mi = 0; mi < 4; mi++) {
            #pragma unroll
            for (int r = 0; r < 4; r++) {
                const int m = m0 + wm * 64 + mi * 16 + quad * 4 + r;
                out[(size_t)m * DIMD + n] = acc[mi][ni][r] + bias;
            }
        }
    }
}

// ---------------------------------------------------------------------------
extern "C" void kernel_launch(void* const* d_in, const int* in_sizes, int n_in,
                              void* d_out, int out_size, void* d_ws, size_t ws_size,
                              hipStream_t stream)
{
    const float* x   = (const float*)d_in[0];
    // d_in[1] = mask: exactly triu(-1e9, k=1) -> causal predicate in-kernel
    const float* qw  = (const float*)d_in[2];
    const float* qb  = (const float*)d_in[3];
    const float* kvw = (const float*)d_in[4];
    const float* kvb = (const float*)d_in[5];
    const float* wow = (const float*)d_in[6];
    const float* wob = (const float*)d_in[7];
    const int*   sp  = (const int*)d_in[8];

    const size_t xN   = (size_t)MROWS * DIMD;
    const size_t qwN  = (size_t)DIMD * DIMD;
    const size_t kvwN = (size_t)2 * KVHD * HDD * DIMD;
    const size_t qN   = (size_t)BSZ4 * NHD  * SEQL * HDD;
    const size_t kvN  = (size_t)BSZ4 * KVHD * SEQL * HDD;

    unsigned short* xb   = (unsigned short*)d_ws;   // [xb|qwb|kvwb|wowb] contiguous
    unsigned short* qwb  = xb   + xN;
    unsigned short* kvwb = qwb  + qwN;
    unsigned short* wowb = kvwb + kvwN;
    unsigned short* Q16  = wowb + qwN;
    unsigned short* K16  = Q16  + qN;
    unsigned short* VT16 = K16  + kvN;
    unsigned short* AO16 = VT16 + kvN;

    cvt_all_kernel<<<CP3 / 256, 256, 0, stream>>>(
        (const float4*)x, (const float4*)qw, (const float4*)kvw,
        (const float4*)wow, (ushort4*)xb);

    qkv_mfma_kernel<<<dim3(NQKV / 128, MROWS / 128, 1), 256, 0, stream>>>(
        xb, qwb, kvwb, qb, kvb, sp, Q16, K16, VT16);
    attn_mfma_kernel<<<dim3(SEQL / 128, NHD, BSZ4), 256, 0, stream>>>(
        Q16, K16, VT16, AO16);
    out_mfma_kernel<<<dim3(DIMD / 128, MROWS / 128, 1), 256, 0, stream>>>(
        AO16, wowb, wob, (float*)d_out);
}

// Round 7
// 419.111 us; speedup vs baseline: 1.1535x; 1.1535x over previous
//
#include <hip/hip_runtime.h>
#include <hip/hip_bf16.h>

// Problem constants
constexpr int DIMD  = 1152;
constexpr int NHD   = 12;     // query heads
constexpr int KVHD  = 2;      // kv heads
constexpr int HDD   = 96;     // head dim
constexpr int GRPS  = 6;      // GQA group size
constexpr int SEQL  = 2048;
constexpr int BSZ4  = 4;
constexpr int MROWS = BSZ4 * SEQL;           // 8192
constexpr int NQKV  = DIMD + 2 * KVHD * HDD; // 1536
constexpr float SCALE2 = 0.14724444f;        // 96^-0.5 * log2(e)

typedef short  bf16x8 __attribute__((ext_vector_type(8)));
typedef float  f32x4  __attribute__((ext_vector_type(4)));
typedef float  f32x16 __attribute__((ext_vector_type(16)));

typedef __attribute__((address_space(3))) unsigned int       lds_u32_t;
typedef __attribute__((address_space(1))) const unsigned int glb_u32_t;

__device__ __forceinline__ void gload16(const unsigned short* g, unsigned short* l) {
    // async global->LDS DMA, 16B/lane; LDS dest = wave-uniform base + lane*16
    __builtin_amdgcn_global_load_lds((glb_u32_t*)(const void*)g,
                                     (lds_u32_t*)(void*)l, 16, 0, 0);
}

__device__ __forceinline__ unsigned short f2bf(float f) {
    unsigned int u = __builtin_bit_cast(unsigned int, f);
    u += 0x7fff + ((u >> 16) & 1);   // RNE
    return (unsigned short)(u >> 16);
}

// ---------------------------------------------------------------------------
// Fused fp32 -> bf16 convert for x | q_w | kv_w | wo_w (dst regions contiguous)
// ---------------------------------------------------------------------------
constexpr int CP0 = (MROWS * DIMD) / 4;                    // x
constexpr int CP1 = CP0 + (DIMD * DIMD) / 4;               // q_w
constexpr int CP2 = CP1 + (2 * KVHD * HDD * DIMD) / 4;     // kv_w
constexpr int CP3 = CP2 + (DIMD * DIMD) / 4;               // wo_w

__global__ __launch_bounds__(256) void cvt_all_kernel(
    const float4* __restrict__ x,   const float4* __restrict__ qw,
    const float4* __restrict__ kvw, const float4* __restrict__ wow,
    ushort4* __restrict__ dst)
{
    int i = blockIdx.x * 256 + threadIdx.x;   // grid == CP3 exactly
    const float4* s; int j;
    if (i < CP0)      { s = x;   j = i; }
    else if (i < CP1) { s = qw;  j = i - CP0; }
    else if (i < CP2) { s = kvw; j = i - CP1; }
    else              { s = wow; j = i - CP2; }
    float4 f = s[j];
    ushort4 o;
    o.x = f2bf(f.x); o.y = f2bf(f.y); o.z = f2bf(f.z); o.w = f2bf(f.w);
    dst[i] = o;
}

// ---------------------------------------------------------------------------
// Kernel 1: QKV projection, bf16 MFMA (m97 structure) + bias + RoPE + scatter
// (unchanged from R3-R6)
// ---------------------------------------------------------------------------
__global__ __launch_bounds__(256) void qkv_mfma_kernel(
    const unsigned short* __restrict__ xb,  const unsigned short* __restrict__ qwb,
    const unsigned short* __restrict__ kvwb,
    const float* __restrict__ qb,  const float* __restrict__ kvb,
    const int* __restrict__ start_pos,
    unsigned short* __restrict__ Qo, unsigned short* __restrict__ Ko,
    unsigned short* __restrict__ VTo)
{
    __shared__ __align__(16) unsigned short As[128 * 32];
    __shared__ __align__(16) unsigned short Bs[128 * 32];

    const int tid  = threadIdx.x;
    const int w    = tid >> 6;
    const int lane = tid & 63;
    const int l16  = lane & 15;
    const int quad = lane >> 4;
    const int wm   = w >> 1, wn = w & 1;
    const int m0   = blockIdx.y * 128;
    const int n0   = blockIdx.x * 128;

    const unsigned short* Abase = xb + (size_t)m0 * DIMD;
    const unsigned short* Bbase = (n0 < DIMD)
        ? qwb  + (size_t)n0 * DIMD
        : kvwb + (size_t)(n0 - DIMD) * DIMD;

    const int srow = w * 16 + (lane >> 2);
    const int scol = (lane & 3) * 8;

    f32x4 acc[4][4];
    #pragma unroll
    for (int mi = 0; mi < 4; mi++)
        #pragma unroll
        for (int ni = 0; ni < 4; ni++) acc[mi][ni] = (f32x4){0.f, 0.f, 0.f, 0.f};

    for (int k0 = 0; k0 < DIMD; k0 += 32) {
        gload16(Abase + (size_t)srow        * DIMD + k0 + scol, &As[w * 512]);
        gload16(Abase + (size_t)(srow + 64) * DIMD + k0 + scol, &As[2048 + w * 512]);
        gload16(Bbase + (size_t)srow        * DIMD + k0 + scol, &Bs[w * 512]);
        gload16(Bbase + (size_t)(srow + 64) * DIMD + k0 + scol, &Bs[2048 + w * 512]);
        __syncthreads();
        bf16x8 af[4], bfr[4];
        #pragma unroll
        for (int mi = 0; mi < 4; mi++)
            af[mi] = *(const bf16x8*)&As[(wm * 64 + mi * 16 + l16) * 32 + quad * 8];
        #pragma unroll
        for (int ni = 0; ni < 4; ni++)
            bfr[ni] = *(const bf16x8*)&Bs[(wn * 64 + ni * 16 + l16) * 32 + quad * 8];
        #pragma unroll
        for (int mi = 0; mi < 4; mi++)
            #pragma unroll
            for (int ni = 0; ni < 4; ni++)
                acc[mi][ni] = __builtin_amdgcn_mfma_f32_16x16x32_bf16(
                    af[mi], bfr[ni], acc[mi][ni], 0, 0, 0);
        __syncthreads();
    }

    const int sp = *start_pos;
    #pragma unroll
    for (int ni = 0; ni < 4; ni++) {
        const int n   = n0 + wn * 64 + ni * 16 + l16;
        const bool isQ = (n < DIMD);
        const int jj  = n - DIMD;
        const bool isK = !isQ && (jj < KVHD * HDD);
        const int d   = isQ ? (n % HDD) : (jj % HDD);
        const int hh  = isQ ? (n / HDD) : ((jj / HDD) & 1);
        const float bias = isQ ? qb[n] : kvb[jj];
        const bool doRope = isQ || isK;
        const int de = d & ~1;
        const float th = doRope ? powf(10000.0f, -(float)de / 96.0f) : 0.0f;
        const float sg = (n & 1) ? 1.0f : -1.0f;
        #pragma unroll
        for (int mi = 0; mi < 4; mi++) {
            #pragma unroll
            for (int r = 0; r < 4; r++) {
                const int m = m0 + wm * 64 + mi * 16 + quad * 4 + r;
                const int b = m >> 11;
                const int s = m & (SEQL - 1);
                float v  = acc[mi][ni][r] + bias;
                float pv = __shfl_xor(v, 1, 64);
                float o = v;
                if (doRope) {
                    float ang = (float)(s + sp) * th;
                    float sn, cs; sincosf(ang, &sn, &cs);
                    o = v * cs + sg * pv * sn;
                }
                if (isQ)
                    Qo[(((size_t)b * NHD + hh) * SEQL + s) * HDD + d] = f2bf(o);
                else if (isK)
                    Ko[(((size_t)b * KVHD + hh) * SEQL + s) * HDD + d] = f2bf(o);
                else
                    VTo[(((size_t)b * KVHD + hh) * HDD + d) * SEQL + s] = f2bf(o);
            }
        }
    }
}

// ---------------------------------------------------------------------------
// Kernel 2: bf16 MFMA causal flash attention, Round 7: 32x32x16 MFMA.
//  - One wave = 32 q-rows as the MFMA 32-wide N dim (Q frags 24 VGPR, not 48).
//  - S^T = K*Q^T: A=K (m=t), B=Q^T (n=q=lane&31). Lane-local softmax over
//    32 t + ONE shfl_xor(32). C/D: col=lane&31, row=(reg&3)+8(reg>>2)+4(lane>>5).
//  - PV: A=P (m=q), B=V^T (n=d), 3 d-tiles x 4 t-steps; P via wave-private LDS.
//  - Single-buffered K/V DMA staging; waves past causal range skip compute.
// LDS: Ks 13.3K + VTs 13.8K + Ps 18K + Al 0.5K = 45 KiB -> 3 WG/CU (12 waves).
// ---------------------------------------------------------------------------
__global__ __launch_bounds__(256, 3) void attn_mfma_kernel(
    const unsigned short* __restrict__ Q, const unsigned short* __restrict__ K,
    const unsigned short* __restrict__ VT, unsigned short* __restrict__ AO)
{
    __shared__ __align__(16) unsigned short Ks[64 * 104];   // t-rows, 13 16B-slots
    __shared__ __align__(16) unsigned short VTs[96 * 72];   // d-rows, 9 16B-slots
    __shared__ __align__(16) unsigned short Ps[4][32 * 72]; // per-wave P [q][t]
    __shared__ float Al[4][32];                             // per-wave bcast

    const int tid  = threadIdx.x;
    const int w    = tid >> 6;
    const int lane = tid & 63;
    const int l32  = lane & 31;
    const int h32  = lane >> 5;
    const int qt   = (int)(gridDim.x - 1) - (int)blockIdx.x;  // heavy first
    const int h    = blockIdx.y;
    const int b    = blockIdx.z;
    const int kvh  = h / GRPS;
    const int nkb  = 2 * qt + 2;

    const unsigned short* Qbase  = Q  + (((size_t)b * NHD  + h)   * SEQL) * HDD;
    const unsigned short* Kbase  = K  + (((size_t)b * KVHD + kvh) * SEQL) * HDD;
    const unsigned short* VTbase = VT + (((size_t)b * KVHD + kvh) * HDD)  * SEQL;

    // --- staging maps: 27 gload16 slots/WG, instr i = w + 4*j (j = 0..6)
    int goff[7]; int gkind[7]; unsigned short* gdst[7];
    #pragma unroll
    for (int j = 0; j < 7; j++) {
        const int i = w + 4 * j;
        gkind[j] = 2; goff[j] = 0; gdst[j] = nullptr;
        if (i < 13) {
            int slot = i * 64 + lane;
            int r = slot / 13, g = slot - r * 13;
            goff[j]  = r * HDD + (g < 12 ? g * 8 : 0);
            gkind[j] = 0;
            gdst[j]  = &Ks[i * 512];
        } else if (i < 27) {
            int iv = i - 13;
            int slot = iv * 64 + lane;
            if (slot < 864) {
                int r = slot / 9, g = slot - r * 9;
                goff[j]  = r * SEQL + (g < 8 ? g * 8 : 0);
                gkind[j] = 1;
                gdst[j]  = &VTs[iv * 512];
            }
        }
    }

    // --- Q B-fragments: q = l32, k-step s covers k in [16s,16s+16)
    const int qw0   = qt * 128 + w * 32;
    const int qlane = qw0 + l32;
    bf16x8 qf[6];
    {
        const unsigned short* qp = Qbase + (size_t)qlane * HDD + h32 * 8;
        #pragma unroll
        for (int s = 0; s < 6; s++) qf[s] = *(const bf16x8*)(qp + 16 * s);
    }

    float m_r = -1e30f, l_r = 0.0f;
    f32x16 oacc[3];
    #pragma unroll
    for (int dt = 0; dt < 3; dt++)
        #pragma unroll
        for (int i = 0; i < 16; i++) oacc[dt][i] = 0.0f;

    for (int kb = 0; kb < nkb; kb++) {
        const int k0 = kb * 64;
        // ---- stage K (64x96) + V^T (96x64) via async DMA (all waves)
        #pragma unroll
        for (int j = 0; j < 7; j++) {
            if (gkind[j] == 0)
                gload16(Kbase + (size_t)k0 * HDD + goff[j], gdst[j]);
            else if (gkind[j] == 1) {
                if ((w + 4 * j) < 26 || lane < 32)
                    gload16(VTbase + k0 + goff[j], gdst[j]);
            }
        }
        __syncthreads();

        if (k0 <= qw0 + 31) {   // wave-uniform: any unmasked t in this block
            // ---- S^T = K * Q^T (two 32-t tiles)
            f32x16 s0, s1;
            #pragma unroll
            for (int i = 0; i < 16; i++) { s0[i] = 0.0f; s1[i] = 0.0f; }
            #pragma unroll
            for (int st = 0; st < 6; st++) {
                bf16x8 a0 = *(const bf16x8*)&Ks[(l32)      * 104 + st * 16 + h32 * 8];
                bf16x8 a1 = *(const bf16x8*)&Ks[(32 + l32) * 104 + st * 16 + h32 * 8];
                s0 = __builtin_amdgcn_mfma_f32_32x32x16_bf16(a0, qf[st], s0, 0, 0, 0);
                s1 = __builtin_amdgcn_mfma_f32_32x32x16_bf16(a1, qf[st], s1, 0, 0, 0);
            }

            // ---- lane-local softmax (q = l32; t = k0 + tile*32 + trow)
            float sc0[16], sc1[16];
            float mx = -3e30f;
            const bool anymask = (k0 + 63 > qw0);   // wave-uniform
            #pragma unroll
            for (int i = 0; i < 16; i++) {
                const int trow = (i & 3) + 8 * (i >> 2) + 4 * h32;
                float x0 = s0[i] * SCALE2;
                float x1 = s1[i] * SCALE2;
                if (anymask) {
                    if (k0 + trow > qlane)      x0 = -1e30f;
                    if (k0 + 32 + trow > qlane) x1 = -1e30f;
                }
                sc0[i] = x0; sc1[i] = x1;
                mx = fmaxf(mx, fmaxf(x0, x1));
            }
            mx = fmaxf(mx, __shfl_xor(mx, 32, 64));
            const float mnew = fmaxf(m_r, mx);
            const float al = exp2f(m_r - mnew);
            float sum = 0.0f;
            #pragma unroll
            for (int rr = 0; rr < 4; rr++) {
                float p0 = exp2f(sc0[rr * 4 + 0] - mnew);
                float p1 = exp2f(sc0[rr * 4 + 1] - mnew);
                float p2 = exp2f(sc0[rr * 4 + 2] - mnew);
                float p3 = exp2f(sc0[rr * 4 + 3] - mnew);
                float p4 = exp2f(sc1[rr * 4 + 0] - mnew);
                float p5 = exp2f(sc1[rr * 4 + 1] - mnew);
                float p6 = exp2f(sc1[rr * 4 + 2] - mnew);
                float p7 = exp2f(sc1[rr * 4 + 3] - mnew);
                sum += ((p0 + p1) + (p2 + p3)) + ((p4 + p5) + (p6 + p7));
                ushort4 pk0, pk1;
                pk0.x = f2bf(p0); pk0.y = f2bf(p1); pk0.z = f2bf(p2); pk0.w = f2bf(p3);
                pk1.x = f2bf(p4); pk1.y = f2bf(p5); pk1.z = f2bf(p6); pk1.w = f2bf(p7);
                *(ushort4*)&Ps[w][l32 * 72 +      rr * 8 + 4 * h32] = pk0;
                *(ushort4*)&Ps[w][l32 * 72 + 32 + rr * 8 + 4 * h32] = pk1;
            }
            sum += __shfl_xor(sum, 32, 64);
            l_r = l_r * al + sum;
            m_r = mnew;
            if (lane < 32) Al[w][lane] = al;
            __builtin_amdgcn_wave_barrier();

            // ---- alpha broadcast (q-row i + 8*rr + 4*h32 per C/D layout)
            float albr[16];
            #pragma unroll
            for (int rr = 0; rr < 4; rr++) {
                float4 a4 = *(const float4*)&Al[w][8 * rr + 4 * h32];
                albr[rr * 4 + 0] = a4.x; albr[rr * 4 + 1] = a4.y;
                albr[rr * 4 + 2] = a4.z; albr[rr * 4 + 3] = a4.w;
            }
            #pragma unroll
            for (int dt = 0; dt < 3; dt++)
                #pragma unroll
                for (int i = 0; i < 16; i++) oacc[dt][i] *= albr[i];

            // ---- O += P V  (A=P reused across 3 d-tiles per t-step)
            #pragma unroll
            for (int st = 0; st < 4; st++) {
                bf16x8 pa = *(const bf16x8*)&Ps[w][l32 * 72 + st * 16 + h32 * 8];
                #pragma unroll
                for (int dt = 0; dt < 3; dt++) {
                    bf16x8 vb = *(const bf16x8*)
                        &VTs[(dt * 32 + l32) * 72 + st * 16 + h32 * 8];
                    oacc[dt] = __builtin_amdgcn_mfma_f32_32x32x16_bf16(
                        pa, vb, oacc[dt], 0, 0, 0);
                }
            }
        }
        __syncthreads();   // all frag reads done before next stage overwrites
    }

    // ---- epilogue: normalize + bf16 store
    const float linv = 1.0f / l_r;
    if (lane < 32) Al[w][lane] = linv;
    __builtin_amdgcn_wave_barrier();
    float lbr[16];
    #pragma unroll
    for (int rr = 0; rr < 4; rr++) {
        float4 l4 = *(const float4*)&Al[w][8 * rr + 4 * h32];
        lbr[rr * 4 + 0] = l4.x; lbr[rr * 4 + 1] = l4.y;
        lbr[rr * 4 + 2] = l4.z; lbr[rr * 4 + 3] = l4.w;
    }
    #pragma unroll
    for (int dt = 0; dt < 3; dt++) {
        #pragma unroll
        for (int i = 0; i < 16; i++) {
            const int row = qw0 + (i & 3) + 8 * (i >> 2) + 4 * h32;
            AO[((size_t)b * SEQL + row) * DIMD + h * HDD + dt * 32 + l32] =
                f2bf(oacc[dt][i] * lbr[i]);
        }
    }
}

// ---------------------------------------------------------------------------
// Kernel 3: output projection, bf16 MFMA (unchanged from R3-R6)
// ---------------------------------------------------------------------------
__global__ __launch_bounds__(256) void out_mfma_kernel(
    const unsigned short* __restrict__ Ab, const unsigned short* __restrict__ Wb,
    const float* __restrict__ wob, float* __restrict__ out)
{
    __shared__ __align__(16) unsigned short As[128 * 32];
    __shared__ __align__(16) unsigned short Bs[128 * 32];

    const int tid  = threadIdx.x;
    const int w    = tid >> 6;
    const int lane = tid & 63;
    const int l16  = lane & 15;
    const int quad = lane >> 4;
    const int wm   = w >> 1, wn = w & 1;
    const int m0   = blockIdx.y * 128;
    const int n0   = blockIdx.x * 128;

    const unsigned short* Abase = Ab + (size_t)m0 * DIMD;
    const unsigned short* Bbase = Wb + (size_t)n0 * DIMD;

    const int srow = w * 16 + (lane >> 2);
    const int scol = (lane & 3) * 8;

    f32x4 acc[4][4];
    #pragma unroll
    for (int mi = 0; mi < 4; mi++)
        #pragma unroll
        for (int ni = 0; ni < 4; ni++) acc[mi][ni] = (f32x4){0.f, 0.f, 0.f, 0.f};

    for (int k0 = 0; k0 < DIMD; k0 += 32) {
        gload16(Abase + (size_t)srow        * DIMD + k0 + scol, &As[w * 512]);
        gload16(Abase + (size_t)(srow + 64) * DIMD + k0 + scol, &As[2048 + w * 512]);
        gload16(Bbase + (size_t)srow        * DIMD + k0 + scol, &Bs[w * 512]);
        gload16(Bbase + (size_t)(srow + 64) * DIMD + k0 + scol, &Bs[2048 + w * 512]);
        __syncthreads();
        bf16x8 af[4], bfr[4];
        #pragma unroll
        for (int mi = 0; mi < 4; mi++)
            af[mi] = *(const bf16x8*)&As[(wm * 64 + mi * 16 + l16) * 32 + quad * 8];
        #pragma unroll
        for (int ni = 0; ni < 4; ni++)
            bfr[ni] = *(const bf16x8*)&Bs[(wn * 64 + ni * 16 + l16) * 32 + quad * 8];
        #pragma unroll
        for (int mi = 0; mi < 4; mi++)
            #pragma unroll
            for (int ni = 0; ni < 4; ni++)
                acc[mi][ni] = __builtin_amdgcn_mfma_f32_16x16x32_bf16(
                    af[mi], bfr[ni], acc[mi][ni], 0, 0, 0);
        __syncthreads();
    }

    #pragma unroll
    for (int ni = 0; ni < 4; ni++) {
        const int n = n0 + wn * 64 + ni * 16 + l16;
        const float bias = wob[n];
        #pragma unroll
        for (int mi = 0; mi < 4; mi++) {
            #pragma unroll
            for (int r = 0; r < 4; r++) {
                const int m = m0 + wm * 64 + mi * 16 + quad * 4 + r;
                out[(size_t)m * DIMD + n] = acc[mi][ni][r] + bias;
            }
        }
    }
}

// ---------------------------------------------------------------------------
extern "C" void kernel_launch(void* const* d_in, const int* in_sizes, int n_in,
                              void* d_out, int out_size, void* d_ws, size_t ws_size,
                              hipStream_t stream)
{
    const float* x   = (const float*)d_in[0];
    // d_in[1] = mask: exactly triu(-1e9, k=1) -> causal predicate in-kernel
    const float* qw  = (const float*)d_in[2];
    const float* qb  = (const float*)d_in[3];
    const float* kvw = (const float*)d_in[4];
    const float* kvb = (const float*)d_in[5];
    const float* wow = (const float*)d_in[6];
    const float* wob = (const float*)d_in[7];
    const int*   sp  = (const int*)d_in[8];

    const size_t xN   = (size_t)MROWS * DIMD;
    const size_t qwN  = (size_t)DIMD * DIMD;
    const size_t kvwN = (size_t)2 * KVHD * HDD * DIMD;
    const size_t qN   = (size_t)BSZ4 * NHD  * SEQL * HDD;
    const size_t kvN  = (size_t)BSZ4 * KVHD * SEQL * HDD;

    unsigned short* xb   = (unsigned short*)d_ws;   // [xb|qwb|kvwb|wowb] contiguous
    unsigned short* qwb  = xb   + xN;
    unsigned short* kvwb = qwb  + qwN;
    unsigned short* wowb = kvwb + kvwN;
    unsigned short* Q16  = wowb + qwN;
    unsigned short* K16  = Q16  + qN;
    unsigned short* VT16 = K16  + kvN;
    unsigned short* AO16 = VT16 + kvN;

    cvt_all_kernel<<<CP3 / 256, 256, 0, stream>>>(
        (const float4*)x, (const float4*)qw, (const float4*)kvw,
        (const float4*)wow, (ushort4*)xb);

    qkv_mfma_kernel<<<dim3(NQKV / 128, MROWS / 128, 1), 256, 0, stream>>>(
        xb, qwb, kvwb, qb, kvb, sp, Q16, K16, VT16);
    attn_mfma_kernel<<<dim3(SEQL / 128, NHD, BSZ4), 256, 0, stream>>>(
        Q16, K16, VT16, AO16);
    out_mfma_kernel<<<dim3(DIMD / 128, MROWS / 128, 1), 256, 0, stream>>>(
        AO16, wowb, wob, (float*)d_out);
}